// Round 3
// baseline (319.422 us; speedup 1.0000x reference)
//
#include <hip/hip_runtime.h>

// Problem constants
#define B_   8
#define TE_  256
#define TD_  256
#define D_   256
#define U_   256

// Workspace layout (float offsets).
#define EET_OFF   0        // (B, U/4, TE, 4) interleaved-transposed Ee
#define ED_OFF    524288   // (B, TD, U)  Ed = exp2(2log2e * de@w_de)
#define MAXMU_OFF 1048576  // (B, TD)     row max of mu'

__device__ __forceinline__ float fexp2(float x) {
#if __has_builtin(__builtin_amdgcn_exp2f)
  return __builtin_amdgcn_exp2f(x);
#else
  return exp2f(x);
#endif
}
__device__ __forceinline__ float frcp(float x) {
#if __has_builtin(__builtin_amdgcn_rcpf)
  return __builtin_amdgcn_rcpf(x);
#else
  return 1.0f / x;
#endif
}

#define LOG2E_F 1.4426950408889634f
#define TWO_LOG2E_F 2.8853900817779268f

#define NBLOCKS 512

// Reusable device-wide generation barrier. Device globals are zero-init at
// module load; generation counting makes it reusable across calls AND across
// graph replays (cnt self-resets; gen monotonically increases).
__device__ int g_cnt;
__device__ int g_gen;

__device__ __forceinline__ void gridbar() {
  __syncthreads();
  if (threadIdx.x == 0) {
    __threadfence();  // make this block's global writes device-visible
    const int gen = __hip_atomic_load(&g_gen, __ATOMIC_RELAXED, __HIP_MEMORY_SCOPE_AGENT);
    const int old = __hip_atomic_fetch_add(&g_cnt, 1, __ATOMIC_ACQ_REL, __HIP_MEMORY_SCOPE_AGENT);
    if (old == NBLOCKS - 1) {
      // reset cnt BEFORE releasing gen (release orders the store)
      __hip_atomic_store(&g_cnt, 0, __ATOMIC_RELAXED, __HIP_MEMORY_SCOPE_AGENT);
      __hip_atomic_fetch_add(&g_gen, 1, __ATOMIC_RELEASE, __HIP_MEMORY_SCOPE_AGENT);
    } else {
      while (__hip_atomic_load(&g_gen, __ATOMIC_ACQUIRE, __HIP_MEMORY_SCOPE_AGENT) == gen)
        __builtin_amdgcn_s_sleep(2);
    }
    __threadfence();  // invalidate stale caches before next phase's reads
  }
  __syncthreads();
}

// ---------------------------------------------------------------------------
// Fused mega-kernel: 512 blocks x 512 threads (2 blocks/CU, all co-resident).
//  Phase A (blocks 0..255): K1 projection GEMMs -> EeT (interleaved) + Ed.
//  gridbar
//  Phase B (all): mu' + fused softmax -> alphas in LDS -> sum_en -> out c0..2,
//                 maxmu to ws.
//  gridbar
//  Phase C (all): per-block softmax over maxmu[b,:], h_hat, out chunk 3.
// ---------------------------------------------------------------------------
__global__ __launch_bounds__(512, 4) void coatt_fused(
    const float* __restrict__ en, const float* __restrict__ de,
    const float* __restrict__ w_en, const float* __restrict__ w_de,
    const float* __restrict__ nu, float* __restrict__ ws,
    float* __restrict__ out) {
  __shared__ union {
    struct { float s[2][2][32][69]; } k1;                 // [A/B][buf][k][rc]
    struct {
      float eds[4][256];
      float nus[256];
      float als[4][256];
      float tp[2][4][256];
      float part[2][8];
      float red[16];
    } k24;
  } sm;

  const int id = blockIdx.x;
  const int tid = threadIdx.x;  // 0..511
  float* __restrict__ eet = ws + EET_OFF;
  float* __restrict__ edp = ws + ED_OFF;
  float* __restrict__ maxmu = ws + MAXMU_OFF;

  // ---------------- Phase A: projections (blocks 0..255) ----------------
  if (id < 256) {
    const int which = id >> 7;          // 0: en->EeT, 1: de->Ed
    const int rem = id & 127;
    const int colBase = (rem & 3) * 64; // col in U
    const int rowBase = (rem >> 2) * 64;// row in (B*T)
    const float* __restrict__ A = which ? de : en;
    const float* __restrict__ W = which ? w_de : w_en;
    // staging roles (512 threads, one float4 of A and one of B each):
    const int aRow = tid >> 3, aC4 = tid & 7;   // 64 rows x 8 f4-k
    const int bK = tid >> 4, bC4 = tid & 15;    // 32 k x 16 f4-col
    // compute roles (first 256 threads own a 4x4 microtile):
    const int tx = tid & 15, ty = (tid >> 4) & 15;
    const bool comp = tid < 256;

    float4 aR = *(const float4*)&A[(size_t)(rowBase + aRow) * D_ + aC4 * 4];
    float4 bR = *(const float4*)&W[(size_t)bK * U_ + colBase + bC4 * 4];
    {
      float v[4]; *(float4*)v = aR;
#pragma unroll
      for (int j = 0; j < 4; ++j) sm.k1.s[0][0][aC4 * 4 + j][aRow] = v[j];
      *(float4*)&sm.k1.s[1][0][bK][bC4 * 4] = bR;
    }
    __syncthreads();

    float acc[4][4] = {};
#define K1_COMPUTE(BUF)                                                  \
    if (comp) {                                                          \
      _Pragma("unroll")                                                  \
      for (int k = 0; k < 32; ++k) {                                     \
        float av[4], bv[4];                                              \
        *(float4*)av = *(const float4*)&sm.k1.s[0][BUF][k][ty * 4];      \
        *(float4*)bv = *(const float4*)&sm.k1.s[1][BUF][k][tx * 4];      \
        _Pragma("unroll")                                                \
        for (int i = 0; i < 4; ++i)                                      \
          _Pragma("unroll")                                              \
          for (int j = 0; j < 4; ++j)                                    \
            acc[i][j] = fmaf(av[i], bv[j], acc[i][j]);                   \
      }                                                                  \
    }

    for (int kc = 0; kc < 7; ++kc) {
      const int k0 = (kc + 1) * 32;
      aR = *(const float4*)&A[(size_t)(rowBase + aRow) * D_ + k0 + aC4 * 4];
      bR = *(const float4*)&W[(size_t)(k0 + bK) * U_ + colBase + bC4 * 4];
      const int cur = kc & 1, nxt = cur ^ 1;
      K1_COMPUTE(cur)
      {
        float v[4]; *(float4*)v = aR;
#pragma unroll
        for (int j = 0; j < 4; ++j) sm.k1.s[0][nxt][aC4 * 4 + j][aRow] = v[j];
        *(float4*)&sm.k1.s[1][nxt][bK][bC4 * 4] = bR;
      }
      __syncthreads();
    }
    K1_COMPUTE(1)

    if (which) {
      if (comp) {
#pragma unroll
        for (int i = 0; i < 4; ++i) {
          float4 o;
          o.x = fexp2(acc[i][0] * TWO_LOG2E_F);
          o.y = fexp2(acc[i][1] * TWO_LOG2E_F);
          o.z = fexp2(acc[i][2] * TWO_LOG2E_F);
          o.w = fexp2(acc[i][3] * TWO_LOG2E_F);
          *(float4*)&edp[(size_t)(rowBase + ty * 4 + i) * U_ + colBase + tx * 4] = o;
        }
      }
    } else {
      __syncthreads();  // smem dead; reuse as transpose buffer
      float* Cs = &sm.k1.s[0][0][0][0];  // 64*69 = 4416 floats needed
      if (comp) {
#pragma unroll
        for (int i = 0; i < 4; ++i)
#pragma unroll
          for (int j = 0; j < 4; ++j)
            Cs[(tx * 4 + j) * 69 + ty * 4 + i] = fexp2(acc[i][j] * TWO_LOG2E_F);
      }
      __syncthreads();
      const int b = rowBase >> 8, t0 = rowBase & 255;
      const int u4Base = colBase >> 2;
#pragma unroll
      for (int kk = 0; kk < 2; ++kk) {
        const int q = tid + 512 * kk;
        const int u4l = q >> 6, tl = q & 63;  // 16 u4-groups x 64 t
        float4 v;
        v.x = Cs[(u4l * 4 + 0) * 69 + tl];
        v.y = Cs[(u4l * 4 + 1) * 69 + tl];
        v.z = Cs[(u4l * 4 + 2) * 69 + tl];
        v.w = Cs[(u4l * 4 + 3) * 69 + tl];
        *(float4*)&eet[(size_t)((b * 64 + u4Base + u4l) * 256 + t0 + tl) * 4] = v;
      }
    }
  }

  gridbar();

  // ---------------- Phase B: mu' + softmax + sum_en (all blocks) ----------
  const int b = id & 7;             // XCD-aligned under round-robin dispatch
  const int sBase = (id >> 3) * 4;
  const int t = tid & 255;
  const int half = tid >> 8;        // 0/1 -> local s rows {0,1}/{2,3}
  const int w = tid >> 6, lane = tid & 63;
  {
    const float2* src = (const float2*)(edp + (size_t)(b * TD_ + sBase) * U_);
    ((float2*)&sm.k24.eds[0][0])[tid] = src[tid];  // 1024 floats
    if (tid < 128) ((float2*)sm.k24.nus)[tid] = ((const float2*)nu)[tid];
  }
  __syncthreads();

  const float* __restrict__ Ee_b = eet + (size_t)b * (U_ * TE_) + t * 4;
  const int s0 = half * 2;
  float accA0 = 0.f, accB0 = 0.f, accA1 = 0.f, accB1 = 0.f;
#pragma unroll 4
  for (int u4 = 0; u4 < 64; ++u4) {
    const float4 ee4 = *(const float4*)&Ee_b[u4 * 1024];        // coalesced 16B
    const float4 nv = *(const float4*)&sm.k24.nus[u4 * 4];      // LDS broadcast
    const float4 d0 = *(const float4*)&sm.k24.eds[s0][u4 * 4];
    const float4 d1 = *(const float4*)&sm.k24.eds[s0 + 1][u4 * 4];
    const float* eep = (const float*)&ee4;
    const float* nvp = (const float*)&nv;
    const float* p0 = (const float*)&d0;
    const float* p1 = (const float*)&d1;
#pragma unroll
    for (int j = 0; j < 4; ++j) {
      const float r0 = frcp(fmaf(p0[j], eep[j], 1.0f));
      const float r1 = frcp(fmaf(p1[j], eep[j], 1.0f));
      if (j & 1) {
        accB0 = fmaf(nvp[j], r0, accB0);
        accB1 = fmaf(nvp[j], r1, accB1);
      } else {
        accA0 = fmaf(nvp[j], r0, accA0);
        accA1 = fmaf(nvp[j], r1, accA1);
      }
    }
  }
  float v0 = -2.f * (accA0 + accB0);
  float v1 = -2.f * (accA1 + accB1);

  float m0 = v0, m1 = v1;
#pragma unroll
  for (int off = 32; off > 0; off >>= 1) {
    m0 = fmaxf(m0, __shfl_xor(m0, off));
    m1 = fmaxf(m1, __shfl_xor(m1, off));
  }
  if (lane == 0) { sm.k24.part[0][w] = m0; sm.k24.part[1][w] = m1; }
  __syncthreads();
  const int wb = half * 4;
  m0 = fmaxf(fmaxf(sm.k24.part[0][wb], sm.k24.part[0][wb + 1]),
             fmaxf(sm.k24.part[0][wb + 2], sm.k24.part[0][wb + 3]));
  m1 = fmaxf(fmaxf(sm.k24.part[1][wb], sm.k24.part[1][wb + 1]),
             fmaxf(sm.k24.part[1][wb + 2], sm.k24.part[1][wb + 3]));
  __syncthreads();
  const float e0 = fexp2((v0 - m0) * LOG2E_F);
  const float e1 = fexp2((v1 - m1) * LOG2E_F);
  float sm0 = e0, sm1 = e1;
#pragma unroll
  for (int off = 32; off > 0; off >>= 1) {
    sm0 += __shfl_xor(sm0, off);
    sm1 += __shfl_xor(sm1, off);
  }
  if (lane == 0) { sm.k24.part[0][w] = sm0; sm.k24.part[1][w] = sm1; }
  __syncthreads();
  const float tot0 = (sm.k24.part[0][wb] + sm.k24.part[0][wb + 1]) +
                     (sm.k24.part[0][wb + 2] + sm.k24.part[0][wb + 3]);
  const float tot1 = (sm.k24.part[1][wb] + sm.k24.part[1][wb + 1]) +
                     (sm.k24.part[1][wb + 2] + sm.k24.part[1][wb + 3]);
  sm.k24.als[s0][t] = e0 * frcp(tot0);
  sm.k24.als[s0 + 1][t] = e1 * frcp(tot1);
  if (t == 0) {
    maxmu[b * TD_ + sBase + s0] = m0;
    maxmu[b * TD_ + sBase + s0 + 1] = m1;
  }
  __syncthreads();

  // sum_en: d = t; halves cover disjoint t-ranges for all 4 s-rows.
  {
    const int d = t;
    const int tBeg = half * 128;
    const float* __restrict__ en_b = en + (size_t)b * TE_ * D_ + d;
    float sa0 = 0.f, sa1 = 0.f, sa2 = 0.f, sa3 = 0.f;
#pragma unroll 4
    for (int t4 = 0; t4 < 32; ++t4) {
      const int tt = tBeg + t4 * 4;
      const float4 a0 = *(const float4*)&sm.k24.als[0][tt];
      const float4 a1 = *(const float4*)&sm.k24.als[1][tt];
      const float4 a2 = *(const float4*)&sm.k24.als[2][tt];
      const float4 a3 = *(const float4*)&sm.k24.als[3][tt];
      float env[4];
#pragma unroll
      for (int j = 0; j < 4; ++j) env[j] = en_b[(size_t)(tt + j) * D_];
      const float* q0 = (const float*)&a0;
      const float* q1 = (const float*)&a1;
      const float* q2 = (const float*)&a2;
      const float* q3 = (const float*)&a3;
#pragma unroll
      for (int j = 0; j < 4; ++j) {
        sa0 = fmaf(q0[j], env[j], sa0);
        sa1 = fmaf(q1[j], env[j], sa1);
        sa2 = fmaf(q2[j], env[j], sa2);
        sa3 = fmaf(q3[j], env[j], sa3);
      }
    }
    sm.k24.tp[half][0][d] = sa0;
    sm.k24.tp[half][1][d] = sa1;
    sm.k24.tp[half][2][d] = sa2;
    sm.k24.tp[half][3][d] = sa3;
    __syncthreads();
#pragma unroll
    for (int k = 0; k < 2; ++k) {
      const int sl = s0 + k;
      const float se = sm.k24.tp[0][sl][d] + sm.k24.tp[1][sl][d];
      const int s = sBase + sl;
      const float dd = de[(size_t)(b * TD_ + s) * D_ + d];
      float* o = out + (size_t)(b * TD_ + s) * (4 * D_);
      o[d] = dd;
      o[D_ + d] = se;
      o[2 * D_ + d] = dd * se;
    }
  }

  gridbar();

  // ---------------- Phase C: softmax over maxmu, h_hat, out chunk 3 -------
  // Every block redundantly computes softmax_s(maxmu[b,:]) and h_hat[b,d]
  // (de panel is L2-resident), then writes chunk 3 for its own 4 s-rows.
  {
    float* ma = sm.k24.als[0];     // 256 floats
    float* red = sm.k24.red;       // 16 floats
    if (tid < 256) {
      const float vv = maxmu[b * TD_ + tid];
      float m = vv;
#pragma unroll
      for (int off = 32; off > 0; off >>= 1) m = fmaxf(m, __shfl_xor(m, off));
      if (lane == 0) red[w] = m;
      __syncthreads();
      m = fmaxf(fmaxf(red[0], red[1]), fmaxf(red[2], red[3]));
      const float e = fexp2((vv - m) * LOG2E_F);
      float s = e;
#pragma unroll
      for (int off = 32; off > 0; off >>= 1) s += __shfl_xor(s, off);
      if (lane == 0) red[8 + w] = s;
      __syncthreads();
      s = (red[8] + red[9]) + (red[10] + red[11]);
      ma[tid] = e * frcp(s);
    } else {
      __syncthreads();
      __syncthreads();
    }
    __syncthreads();
    // h_hat for all d; halves split the s-range.
    const int d = t;
    float acc = 0.f;
    const float* __restrict__ de_b = de + (size_t)b * TD_ * D_ + d;
#pragma unroll 4
    for (int s = half * 128; s < half * 128 + 128; ++s)
      acc = fmaf(de_b[(size_t)s * D_], ma[s], acc);
    sm.k24.tp[half][0][d] = acc;
    __syncthreads();
    const float hh = sm.k24.tp[0][0][d] + sm.k24.tp[1][0][d];
#pragma unroll
    for (int k = 0; k < 2; ++k) {
      const int s = sBase + half * 2 + k;
      const float dd = de[(size_t)(b * TD_ + s) * D_ + d];
      out[(size_t)(b * TD_ + s) * (4 * D_) + 3 * D_ + d] = dd * hh;
    }
  }
}

extern "C" void kernel_launch(void* const* d_in, const int* in_sizes, int n_in,
                              void* d_out, int out_size, void* d_ws, size_t ws_size,
                              hipStream_t stream) {
  (void)in_sizes; (void)n_in; (void)out_size; (void)ws_size;
  const float* en   = (const float*)d_in[0];
  const float* de   = (const float*)d_in[1];
  const float* w_en = (const float*)d_in[2];
  const float* w_de = (const float*)d_in[3];
  const float* nu   = (const float*)d_in[4];
  float* out = (float*)d_out;
  float* ws  = (float*)d_ws;

  coatt_fused<<<dim3(NBLOCKS), 512, 0, stream>>>(en, de, w_en, w_de, nu, ws, out);
}

// Round 4
// 210.594 us; speedup vs baseline: 1.5168x; 1.5168x over previous
//
#include <hip/hip_runtime.h>

// Problem constants
#define B_   8
#define TE_  256
#define TD_  256
#define D_   256
#define U_   256

// Workspace layout (float offsets). ~4.2 MB.
// EeT is stored INTERLEAVED: EeT[b][u4][t][j] = exp2(2log2e*ae[b,t,4*u4+j])
// so the K24 u-loop reads one float4 (4 u-values) per lane per iteration.
#define EET_OFF   0        // (B, U/4, TE, 4)
#define ED_OFF    524288   // (B, TD, U)  Ed = exp2(2log2e * de@w_de), row-major
#define MAXMU_OFF 1048576  // (B, TD)     row max of mu'

__device__ __forceinline__ float fexp2(float x) {
#if __has_builtin(__builtin_amdgcn_exp2f)
  return __builtin_amdgcn_exp2f(x);
#else
  return exp2f(x);
#endif
}
__device__ __forceinline__ float frcp(float x) {
#if __has_builtin(__builtin_amdgcn_rcpf)
  return __builtin_amdgcn_rcpf(x);
#else
  return 1.0f / x;
#endif
}

#define LOG2E_F 1.4426950408889634f
#define TWO_LOG2E_F 2.8853900817779268f

// ---------------------------------------------------------------------------
// K1: Ed = exp2(2log2e * de@w_de) row-major; Ee -> interleaved-transposed
// EeT[b][u4][t][j] via LDS transpose epilogue. 64x64 tile, 4x4 microtile,
// K-chunks of 32, double-buffered, 256 threads. grid (4, 32, 2) = 256 blocks.
// (Identical to R2 best-known-good.)
// ---------------------------------------------------------------------------
__global__ __launch_bounds__(256) void coatt_k1_proj(
    const float* __restrict__ en, const float* __restrict__ de,
    const float* __restrict__ w_en, const float* __restrict__ w_de,
    float* __restrict__ ws) {
  const int which = blockIdx.z;  // 0: en->EeT (interleaved), 1: de->Ed (direct)
  const float* __restrict__ A = which ? de : en;     // (2048, 256)
  const float* __restrict__ W = which ? w_de : w_en; // (256, 256)
  const int rowBase = blockIdx.y * 64;   // global row in (B*T)
  const int colBase = blockIdx.x * 64;   // col in U
  __shared__ float smem[2][2][32][69];   // [A/B][buf][k][rowOrCol], pitch 69
  const int tid = threadIdx.x;
  const int tx = tid & 15, ty = tid >> 4;      // compute: col0=tx*4, row0=ty*4
  const int aRow0 = tid >> 3, aC4 = tid & 7;   // A stage: 32 rows x 8 f4-k (+32)
  const int bK0 = tid >> 4, bC4 = tid & 15;    // B stage: 16 k x 16 f4-col (+16)
  float4 aR[2], bR[2];

  // prologue: chunk 0
#pragma unroll
  for (int kk = 0; kk < 2; ++kk) {
    aR[kk] = *(const float4*)&A[(size_t)(rowBase + aRow0 + 32 * kk) * D_ + aC4 * 4];
    bR[kk] = *(const float4*)&W[(size_t)(bK0 + 16 * kk) * U_ + colBase + bC4 * 4];
  }
#pragma unroll
  for (int kk = 0; kk < 2; ++kk) {
    float v[4]; *(float4*)v = aR[kk];
#pragma unroll
    for (int j = 0; j < 4; ++j) smem[0][0][aC4 * 4 + j][aRow0 + 32 * kk] = v[j];
    *(float4*)&smem[1][0][bK0 + 16 * kk][bC4 * 4] = bR[kk];
  }
  __syncthreads();

  float acc[4][4] = {};
#define K1_COMPUTE(BUF)                                              \
  _Pragma("unroll")                                                  \
  for (int k = 0; k < 32; ++k) {                                     \
    float av[4], bv[4];                                              \
    *(float4*)av = *(const float4*)&smem[0][BUF][k][ty * 4];         \
    *(float4*)bv = *(const float4*)&smem[1][BUF][k][tx * 4];         \
    _Pragma("unroll")                                                \
    for (int i = 0; i < 4; ++i)                                      \
      _Pragma("unroll")                                              \
      for (int j = 0; j < 4; ++j)                                    \
        acc[i][j] = fmaf(av[i], bv[j], acc[i][j]);                   \
  }

  for (int kc = 0; kc < 7; ++kc) {
    const int k0 = (kc + 1) * 32;
#pragma unroll
    for (int kk = 0; kk < 2; ++kk) {
      aR[kk] = *(const float4*)&A[(size_t)(rowBase + aRow0 + 32 * kk) * D_ + k0 + aC4 * 4];
      bR[kk] = *(const float4*)&W[(size_t)(k0 + bK0 + 16 * kk) * U_ + colBase + bC4 * 4];
    }
    const int cur = kc & 1, nxt = cur ^ 1;
    K1_COMPUTE(cur)
#pragma unroll
    for (int kk = 0; kk < 2; ++kk) {
      float v[4]; *(float4*)v = aR[kk];
#pragma unroll
      for (int j = 0; j < 4; ++j) smem[0][nxt][aC4 * 4 + j][aRow0 + 32 * kk] = v[j];
      *(float4*)&smem[1][nxt][bK0 + 16 * kk][bC4 * 4] = bR[kk];
    }
    __syncthreads();
  }
  K1_COMPUTE(1)

  if (which) {
    // Ed: direct row-major float4 store
    float* __restrict__ outp = ws + ED_OFF;
#pragma unroll
    for (int i = 0; i < 4; ++i) {
      float4 o;
      o.x = fexp2(acc[i][0] * TWO_LOG2E_F);
      o.y = fexp2(acc[i][1] * TWO_LOG2E_F);
      o.z = fexp2(acc[i][2] * TWO_LOG2E_F);
      o.w = fexp2(acc[i][3] * TWO_LOG2E_F);
      *(float4*)&outp[(size_t)(rowBase + ty * 4 + i) * U_ + colBase + tx * 4] = o;
    }
  } else {
    // EeT interleaved: Cs[u_local][t_local] (pitch 69), then gather 4
    // consecutive-u values into a float4 at [b][u4][t][4] (contiguous stores).
    __syncthreads();  // smem dead after last compute; reuse as Cs
    float* Cs = &smem[0][0][0][0];  // need 64*69 = 4416 <= 8832 floats
#pragma unroll
    for (int i = 0; i < 4; ++i)
#pragma unroll
      for (int j = 0; j < 4; ++j)
        Cs[(tx * 4 + j) * 69 + ty * 4 + i] = fexp2(acc[i][j] * TWO_LOG2E_F);
    __syncthreads();
    float* __restrict__ outp = ws + EET_OFF;
    const int b = rowBase >> 8, t0 = rowBase & 255;
    const int u4Base = colBase >> 2;
#pragma unroll
    for (int kk = 0; kk < 4; ++kk) {
      const int q = tid + 256 * kk;
      const int u4l = q >> 6, tl = q & 63;  // 16 u4-groups x 64 t
      float4 v;
      v.x = Cs[(u4l * 4 + 0) * 69 + tl];
      v.y = Cs[(u4l * 4 + 1) * 69 + tl];
      v.z = Cs[(u4l * 4 + 2) * 69 + tl];
      v.w = Cs[(u4l * 4 + 3) * 69 + tl];
      *(float4*)&outp[(size_t)((b * 64 + u4Base + u4l) * 256 + t0 + tl) * 4] = v;
    }
  }
}

// ---------------------------------------------------------------------------
// K24 (fused K2+K4), 512 threads. Identical to R2 best-known-good.
// IDEMPOTENT: reads en/de/nu/ws, writes maxmu + out chunks 0..2
// deterministically -> safe to relaunch for timing attribution.
// ---------------------------------------------------------------------------
__global__ __launch_bounds__(512) void coatt_k24(
    const float* __restrict__ en, const float* __restrict__ de,
    const float* __restrict__ nu, float* __restrict__ ws,
    float* __restrict__ out) {
  const float* __restrict__ EeT = ws + EET_OFF;
  const float* __restrict__ Ed = ws + ED_OFF;
  float* __restrict__ maxmu = ws + MAXMU_OFF;
  const int id = blockIdx.x;
  const int b = id & 7;             // XCD-aligned: id%8 tracks XCD assignment
  const int sBase = (id >> 3) * 4;
  const int tid = threadIdx.x;      // 0..511
  const int t = tid & 255;
  const int half = tid >> 8;        // 0/1 -> local s rows {0,1} / {2,3}
  const int w = tid >> 6, lane = tid & 63;

  __shared__ float eds[4][256];   // 4 Ed rows
  __shared__ float nus[256];
  __shared__ float als[4][256];   // alphas
  __shared__ float tp[2][4][256]; // t-phase partials [half][s][d]
  __shared__ float part[2][8];    // softmax partials [s-local-in-half][wave]

  // Preload Ed rows + nu into LDS (coalesced float2).
  {
    const float2* src = (const float2*)(Ed + (size_t)(b * TD_ + sBase) * U_);
    ((float2*)&eds[0][0])[tid] = src[tid];  // 512 float2 = 1024 floats
    if (tid < 128) ((float2*)nus)[tid] = ((const float2*)nu)[tid];
  }
  __syncthreads();

  const float* __restrict__ Ee_b = EeT + (size_t)b * (U_ * TE_) + t * 4;
  const int s0 = half * 2;
  float accA0 = 0.f, accB0 = 0.f, accA1 = 0.f, accB1 = 0.f;  // 2 chains per s
#pragma unroll 4
  for (int u4 = 0; u4 < 64; ++u4) {
    const float4 ee4 = *(const float4*)&Ee_b[u4 * 1024];        // coalesced 16B
    const float4 nv = *(const float4*)&nus[u4 * 4];             // LDS broadcast
    const float4 d0 = *(const float4*)&eds[s0][u4 * 4];
    const float4 d1 = *(const float4*)&eds[s0 + 1][u4 * 4];
    const float* eep = (const float*)&ee4;
    const float* nvp = (const float*)&nv;
    const float* p0 = (const float*)&d0;
    const float* p1 = (const float*)&d1;
#pragma unroll
    for (int j = 0; j < 4; ++j) {
      const float r0 = frcp(fmaf(p0[j], eep[j], 1.0f));
      const float r1 = frcp(fmaf(p1[j], eep[j], 1.0f));
      if (j & 1) {
        accB0 = fmaf(nvp[j], r0, accB0);
        accB1 = fmaf(nvp[j], r1, accB1);
      } else {
        accA0 = fmaf(nvp[j], r0, accA0);
        accA1 = fmaf(nvp[j], r1, accA1);
      }
    }
  }
  float v0 = -2.f * (accA0 + accB0);
  float v1 = -2.f * (accA1 + accB1);

  // Softmax over t for the 2 local s-rows; each covered by the half's 4 waves.
  float m0 = v0, m1 = v1;
#pragma unroll
  for (int off = 32; off > 0; off >>= 1) {
    m0 = fmaxf(m0, __shfl_xor(m0, off));
    m1 = fmaxf(m1, __shfl_xor(m1, off));
  }
  if (lane == 0) { part[0][w] = m0; part[1][w] = m1; }
  __syncthreads();
  const int wb = half * 4;
  m0 = fmaxf(fmaxf(part[0][wb], part[0][wb + 1]), fmaxf(part[0][wb + 2], part[0][wb + 3]));
  m1 = fmaxf(fmaxf(part[1][wb], part[1][wb + 1]), fmaxf(part[1][wb + 2], part[1][wb + 3]));
  __syncthreads();
  const float e0 = fexp2((v0 - m0) * LOG2E_F);
  const float e1 = fexp2((v1 - m1) * LOG2E_F);
  float sm0 = e0, sm1 = e1;
#pragma unroll
  for (int off = 32; off > 0; off >>= 1) {
    sm0 += __shfl_xor(sm0, off);
    sm1 += __shfl_xor(sm1, off);
  }
  if (lane == 0) { part[0][w] = sm0; part[1][w] = sm1; }
  __syncthreads();
  const float tot0 = (part[0][wb] + part[0][wb + 1]) + (part[0][wb + 2] + part[0][wb + 3]);
  const float tot1 = (part[1][wb] + part[1][wb + 1]) + (part[1][wb + 2] + part[1][wb + 3]);
  als[s0][t] = e0 * frcp(tot0);
  als[s0 + 1][t] = e1 * frcp(tot1);
  if (t == 0) {
    maxmu[b * TD_ + sBase + s0] = m0;
    maxmu[b * TD_ + sBase + s0 + 1] = m1;
  }
  __syncthreads();

  // Phase t: d = t; halves cover disjoint t-ranges for ALL 4 s-rows.
  const int d = t;
  const int tBeg = half * 128;
  const float* __restrict__ en_b = en + (size_t)b * TE_ * D_ + d;
  float sa0 = 0.f, sa1 = 0.f, sa2 = 0.f, sa3 = 0.f;
#pragma unroll 4
  for (int t4 = 0; t4 < 32; ++t4) {
    const int tt = tBeg + t4 * 4;
    const float4 a0 = *(const float4*)&als[0][tt];  // LDS broadcast
    const float4 a1 = *(const float4*)&als[1][tt];
    const float4 a2 = *(const float4*)&als[2][tt];
    const float4 a3 = *(const float4*)&als[3][tt];
    float env[4];
#pragma unroll
    for (int j = 0; j < 4; ++j) env[j] = en_b[(size_t)(tt + j) * D_];  // coalesced
    const float* q0 = (const float*)&a0;
    const float* q1 = (const float*)&a1;
    const float* q2 = (const float*)&a2;
    const float* q3 = (const float*)&a3;
#pragma unroll
    for (int j = 0; j < 4; ++j) {
      sa0 = fmaf(q0[j], env[j], sa0);
      sa1 = fmaf(q1[j], env[j], sa1);
      sa2 = fmaf(q2[j], env[j], sa2);
      sa3 = fmaf(q3[j], env[j], sa3);
    }
  }
  tp[half][0][d] = sa0;
  tp[half][1][d] = sa1;
  tp[half][2][d] = sa2;
  tp[half][3][d] = sa3;
  __syncthreads();
#pragma unroll
  for (int k = 0; k < 2; ++k) {
    const int sl = s0 + k;
    const float se = tp[0][sl][d] + tp[1][sl][d];
    const int s = sBase + sl;
    const float dd = de[(size_t)(b * TD_ + s) * D_ + d];
    float* o = out + (size_t)(b * TD_ + s) * (4 * D_);
    o[d] = dd;
    o[D_ + d] = se;
    o[2 * D_ + d] = dd * se;
  }
}

// ---------------------------------------------------------------------------
// K3: max_alphas = softmax_s(maxmu[b,:]); h_hat[b,dchunk] = sum_s de*ma[s];
// then writes out chunk 3 = de * h_hat for all s at its 32 d-columns.
// grid (8 dChunks, 8 b), 256 threads. Identical to R2.
// ---------------------------------------------------------------------------
__global__ __launch_bounds__(256) void coatt_k3_hhat(
    const float* __restrict__ de, const float* __restrict__ ws,
    float* __restrict__ out) {
  const float* __restrict__ maxmu = ws + MAXMU_OFF;
  const int b = blockIdx.y;
  const int dBase = blockIdx.x * 32;
  const int tid = threadIdx.x;
  const int w = tid >> 6, lane = tid & 63;
  __shared__ float red[8];
  __shared__ float malpha[256];
  __shared__ float acc_red[256];
  __shared__ float hh_s[32];
  const float vv = maxmu[b * TD_ + tid];
  float m = vv;
#pragma unroll
  for (int off = 32; off > 0; off >>= 1) m = fmaxf(m, __shfl_xor(m, off));
  if (lane == 0) red[w] = m;
  __syncthreads();
  m = fmaxf(fmaxf(red[0], red[1]), fmaxf(red[2], red[3]));
  const float e = fexp2((vv - m) * LOG2E_F);
  float sm = e;
#pragma unroll
  for (int off = 32; off > 0; off >>= 1) sm += __shfl_xor(sm, off);
  if (lane == 0) red[4 + w] = sm;
  __syncthreads();
  sm = (red[4] + red[5]) + (red[6] + red[7]);
  malpha[tid] = e * frcp(sm);
  __syncthreads();
  const int dl = tid & 31, sg = tid >> 5;
  float acc = 0.f;
  for (int s = sg * 32; s < sg * 32 + 32; ++s)
    acc = fmaf(de[(size_t)(b * TD_ + s) * D_ + dBase + dl], malpha[s], acc);
  acc_red[tid] = acc;
  __syncthreads();
  if (tid < 32) {
    float tsum = acc_red[tid];
#pragma unroll
    for (int g = 1; g < 8; ++g) tsum += acc_red[g * 32 + tid];
    hh_s[tid] = tsum;
  }
  __syncthreads();
  const float hh = hh_s[dl];
#pragma unroll 4
  for (int s = sg; s < TD_; s += 8) {
    const float dd = de[(size_t)(b * TD_ + s) * D_ + dBase + dl];
    out[(size_t)(b * TD_ + s) * (4 * D_) + 3 * D_ + dBase + dl] = dd * hh;
  }
}

extern "C" void kernel_launch(void* const* d_in, const int* in_sizes, int n_in,
                              void* d_out, int out_size, void* d_ws, size_t ws_size,
                              hipStream_t stream) {
  (void)in_sizes; (void)n_in; (void)out_size; (void)ws_size;
  const float* en   = (const float*)d_in[0];
  const float* de   = (const float*)d_in[1];
  const float* w_en = (const float*)d_in[2];
  const float* w_de = (const float*)d_in[3];
  const float* nu   = (const float*)d_in[4];
  float* out = (float*)d_out;
  float* ws  = (float*)d_ws;

  coatt_k1_proj<<<dim3(4, 32, 2), 256, 0, stream>>>(en, de, w_en, w_de, ws);
  coatt_k24<<<dim3(512), 512, 0, stream>>>(en, de, nu, ws, out);
  coatt_k3_hhat<<<dim3(8, 8), 256, 0, stream>>>(de, ws, out);
  // --- ATTRIBUTION INSTRUMENTATION (this round only) ---
  // K24 is idempotent; 4 extra launches amplify its timing contribution 5x.
  // dur_us = base + 4*(T_k24 + launch_overhead). Output is bit-identical.
  coatt_k24<<<dim3(512), 512, 0, stream>>>(en, de, nu, ws, out);
  coatt_k24<<<dim3(512), 512, 0, stream>>>(en, de, nu, ws, out);
  coatt_k24<<<dim3(512), 512, 0, stream>>>(en, de, nu, ws, out);
  coatt_k24<<<dim3(512), 512, 0, stream>>>(en, de, nu, ws, out);
}

// Round 5
// 150.589 us; speedup vs baseline: 2.1212x; 1.3985x over previous
//
#include <hip/hip_runtime.h>

// Problem constants
#define B_   8
#define TE_  256
#define TD_  256
#define D_   256
#define U_   256

// Workspace layout (float offsets). ~4.2 MB.
// EeT is stored INTERLEAVED: EeT[b][u4][t][j] = exp2(2log2e*ae[b,t,4*u4+j])
// so the K24 u-loop reads one float4 (4 u-values) per lane per iteration.
#define EET_OFF   0        // (B, U/4, TE, 4)
#define ED_OFF    524288   // (B, TD, U)  Ed = exp2(2log2e * de@w_de), row-major
#define MAXMU_OFF 1048576  // (B, TD)     row max of mu'

__device__ __forceinline__ float fexp2(float x) {
#if __has_builtin(__builtin_amdgcn_exp2f)
  return __builtin_amdgcn_exp2f(x);
#else
  return exp2f(x);
#endif
}
__device__ __forceinline__ float frcp(float x) {
#if __has_builtin(__builtin_amdgcn_rcpf)
  return __builtin_amdgcn_rcpf(x);
#else
  return 1.0f / x;
#endif
}

#define LOG2E_F 1.4426950408889634f
#define TWO_LOG2E_F 2.8853900817779268f

// ---------------------------------------------------------------------------
// K1 v3: ZERO-LDS main loop. 64x64 tile, 4x4 microtile, 256 threads,
// grid (4, 32, 2) = 256 blocks.
//   A reads: 16 lanes share each address -> VMEM coalescer dedups to one L1
//     fetch (broadcast). B reads: 16 distinct dwordx4 spanning 256B, L1-hot
//     (W-tile active set 16KB/chunk << 32KB L1). No staging, no barriers in
//     the k-loop -> no LDS-pipe bottleneck (was ~536 MB LDS traffic = 10+ us)
//     and no barrier-drain at 1 wave/SIMD.
// LDS only in the which==0 transpose epilogue (Cs).
// ---------------------------------------------------------------------------
__global__ __launch_bounds__(256) void coatt_k1_proj(
    const float* __restrict__ en, const float* __restrict__ de,
    const float* __restrict__ w_en, const float* __restrict__ w_de,
    float* __restrict__ eet, float* __restrict__ edp) {
  const int which = blockIdx.z;  // 0: en->EeT (interleaved), 1: de->Ed (direct)
  const float* __restrict__ A = which ? de : en;     // (2048, 256)
  const float* __restrict__ W = which ? w_de : w_en; // (256, 256)
  const int rowBase = blockIdx.y * 64;   // global row in (B*T)
  const int colBase = blockIdx.x * 64;   // col in U
  __shared__ float Cs[64][69];           // transpose epilogue only
  const int tid = threadIdx.x;
  const int tx = tid & 15, ty = tid >> 4;  // cols tx*4.., rows ty*4..

  float acc[4][4] = {};
#pragma unroll 4
  for (int k4 = 0; k4 < 64; ++k4) {
    float a[4][4];
#pragma unroll
    for (int i = 0; i < 4; ++i)
      *(float4*)a[i] =
          *(const float4*)&A[(size_t)(rowBase + ty * 4 + i) * D_ + k4 * 4];
#pragma unroll
    for (int kk = 0; kk < 4; ++kk) {
      float bv[4];
      *(float4*)bv =
          *(const float4*)&W[(size_t)(k4 * 4 + kk) * U_ + colBase + tx * 4];
#pragma unroll
      for (int i = 0; i < 4; ++i)
#pragma unroll
        for (int j = 0; j < 4; ++j)
          acc[i][j] = fmaf(a[i][kk], bv[j], acc[i][j]);
    }
  }

  if (which) {
    // Ed: direct row-major float4 store
#pragma unroll
    for (int i = 0; i < 4; ++i) {
      float4 o;
      o.x = fexp2(acc[i][0] * TWO_LOG2E_F);
      o.y = fexp2(acc[i][1] * TWO_LOG2E_F);
      o.z = fexp2(acc[i][2] * TWO_LOG2E_F);
      o.w = fexp2(acc[i][3] * TWO_LOG2E_F);
      *(float4*)&edp[(size_t)(rowBase + ty * 4 + i) * U_ + colBase + tx * 4] = o;
    }
  } else {
    // EeT interleaved: Cs[u_local][t_local] (pitch 69), then gather 4
    // consecutive-u values into a float4 at [b][u4][t][4] (contiguous stores).
#pragma unroll
    for (int i = 0; i < 4; ++i)
#pragma unroll
      for (int j = 0; j < 4; ++j)
        Cs[tx * 4 + j][ty * 4 + i] = fexp2(acc[i][j] * TWO_LOG2E_F);
    __syncthreads();
    const int b = rowBase >> 8, t0 = rowBase & 255;
    const int u4Base = colBase >> 2;
#pragma unroll
    for (int kk = 0; kk < 4; ++kk) {
      const int q = tid + 256 * kk;
      const int u4l = q >> 6, tl = q & 63;  // 16 u4-groups x 64 t
      float4 v;
      v.x = Cs[u4l * 4 + 0][tl];
      v.y = Cs[u4l * 4 + 1][tl];
      v.z = Cs[u4l * 4 + 2][tl];
      v.w = Cs[u4l * 4 + 3][tl];
      *(float4*)&eet[(size_t)((b * 64 + u4Base + u4l) * 256 + t0 + tl) * 4] = v;
    }
  }
}

// ---------------------------------------------------------------------------
// K24 v3 (fused K2+K4), 512 threads, grid 512 (2 blocks/CU, 4 waves/SIMD).
// Phase u: mu'[s][t] = -2 * sum_u nu_u * rcp(fma(Ed[s,u], Ee[t,u], 1))
//   Ee: one coalesced global dwordx4 per 4 u (interleaved layout, vector).
//   Ed/nu: wave-uniform -> SGPR base via readfirstlane + separate __restrict__
//   args => s_load_dwordx4 on the SMEM pipe. ZERO LDS in the u-loop (R2's
//   LDS preload saturated the LDS pipe: 192 ds_read_b128/wave removed).
// Fused softmax over t -> alphas in LDS; maxmu written for K3.
// Phase t: halves cover disjoint t-ranges; partials combined via LDS.
// Writes out chunks 0..2; chunk 3 deferred to K3.
// ---------------------------------------------------------------------------
__global__ __launch_bounds__(512) void coatt_k24(
    const float* __restrict__ en, const float* __restrict__ de,
    const float* __restrict__ nu, const float* __restrict__ eet,
    const float* __restrict__ edp, float* __restrict__ maxmu,
    float* __restrict__ out) {
  const int id = blockIdx.x;
  const int b = id & 7;             // XCD-aligned under round-robin dispatch
  const int sBase = (id >> 3) * 4;
  const int tid = threadIdx.x;      // 0..511
  const int t = tid & 255;
  const int half = tid >> 8;        // 0/1 -> local s rows {0,1} / {2,3}
  const int w = tid >> 6, lane = tid & 63;

  __shared__ float als[4][256];   // alphas
  __shared__ float tp[2][4][256]; // t-phase partials [half][s][d]
  __shared__ float part[2][8];    // softmax partials [s-local-in-half][wave]

  // Wave-uniform Ed row base -> SGPR (readfirstlane). half is wave-uniform.
  const int edBase =
      __builtin_amdgcn_readfirstlane((b * TD_ + sBase + half * 2) * U_);
  const float* __restrict__ Ed0 = edp + edBase;        // uniform -> s_load
  const float* __restrict__ Ed1 = Ed0 + U_;
  const float* __restrict__ Ee_b = eet + (size_t)b * (U_ * TE_) + t * 4;

  float accA0 = 0.f, accB0 = 0.f, accA1 = 0.f, accB1 = 0.f;  // 2 chains per s
#pragma unroll 4
  for (int u4 = 0; u4 < 64; ++u4) {
    const float4 ee4 = *(const float4*)&Ee_b[u4 * 1024];  // coalesced 16B
    const float4 nv = *(const float4*)&nu[u4 * 4];        // uniform -> SGPR
    const float4 d0 = *(const float4*)&Ed0[u4 * 4];       // uniform -> SGPR
    const float4 d1 = *(const float4*)&Ed1[u4 * 4];       // uniform -> SGPR
    const float* eep = (const float*)&ee4;
    const float* nvp = (const float*)&nv;
    const float* p0 = (const float*)&d0;
    const float* p1 = (const float*)&d1;
#pragma unroll
    for (int j = 0; j < 4; ++j) {
      const float r0 = frcp(fmaf(p0[j], eep[j], 1.0f));
      const float r1 = frcp(fmaf(p1[j], eep[j], 1.0f));
      if (j & 1) {
        accB0 = fmaf(nvp[j], r0, accB0);
        accB1 = fmaf(nvp[j], r1, accB1);
      } else {
        accA0 = fmaf(nvp[j], r0, accA0);
        accA1 = fmaf(nvp[j], r1, accA1);
      }
    }
  }
  float v0 = -2.f * (accA0 + accB0);
  float v1 = -2.f * (accA1 + accB1);

  // Softmax over t for the 2 local s-rows; each covered by the half's 4 waves.
  float m0 = v0, m1 = v1;
#pragma unroll
  for (int off = 32; off > 0; off >>= 1) {
    m0 = fmaxf(m0, __shfl_xor(m0, off));
    m1 = fmaxf(m1, __shfl_xor(m1, off));
  }
  if (lane == 0) { part[0][w] = m0; part[1][w] = m1; }
  __syncthreads();
  const int wb = half * 4;
  m0 = fmaxf(fmaxf(part[0][wb], part[0][wb + 1]),
             fmaxf(part[0][wb + 2], part[0][wb + 3]));
  m1 = fmaxf(fmaxf(part[1][wb], part[1][wb + 1]),
             fmaxf(part[1][wb + 2], part[1][wb + 3]));
  __syncthreads();
  const float e0 = fexp2((v0 - m0) * LOG2E_F);
  const float e1 = fexp2((v1 - m1) * LOG2E_F);
  float sm0 = e0, sm1 = e1;
#pragma unroll
  for (int off = 32; off > 0; off >>= 1) {
    sm0 += __shfl_xor(sm0, off);
    sm1 += __shfl_xor(sm1, off);
  }
  if (lane == 0) { part[0][w] = sm0; part[1][w] = sm1; }
  __syncthreads();
  const float tot0 = (part[0][wb] + part[0][wb + 1]) +
                     (part[0][wb + 2] + part[0][wb + 3]);
  const float tot1 = (part[1][wb] + part[1][wb + 1]) +
                     (part[1][wb + 2] + part[1][wb + 3]);
  const int s0 = half * 2;
  als[s0][t] = e0 * frcp(tot0);
  als[s0 + 1][t] = e1 * frcp(tot1);
  if (t == 0) {
    maxmu[b * TD_ + sBase + s0] = m0;
    maxmu[b * TD_ + sBase + s0 + 1] = m1;
  }
  __syncthreads();

  // Phase t: d = t; halves cover disjoint t-ranges for ALL 4 s-rows.
  const int d = t;
  const int tBeg = half * 128;
  const float* __restrict__ en_b = en + (size_t)b * TE_ * D_ + d;
  float sa0 = 0.f, sa1 = 0.f, sa2 = 0.f, sa3 = 0.f;
#pragma unroll 4
  for (int t4 = 0; t4 < 32; ++t4) {
    const int tt = tBeg + t4 * 4;
    const float4 a0 = *(const float4*)&als[0][tt];  // LDS broadcast
    const float4 a1 = *(const float4*)&als[1][tt];
    const float4 a2 = *(const float4*)&als[2][tt];
    const float4 a3 = *(const float4*)&als[3][tt];
    float env[4];
#pragma unroll
    for (int j = 0; j < 4; ++j) env[j] = en_b[(size_t)(tt + j) * D_];  // coalesced
    const float* q0 = (const float*)&a0;
    const float* q1 = (const float*)&a1;
    const float* q2 = (const float*)&a2;
    const float* q3 = (const float*)&a3;
#pragma unroll
    for (int j = 0; j < 4; ++j) {
      sa0 = fmaf(q0[j], env[j], sa0);
      sa1 = fmaf(q1[j], env[j], sa1);
      sa2 = fmaf(q2[j], env[j], sa2);
      sa3 = fmaf(q3[j], env[j], sa3);
    }
  }
  tp[half][0][d] = sa0;
  tp[half][1][d] = sa1;
  tp[half][2][d] = sa2;
  tp[half][3][d] = sa3;
  __syncthreads();
#pragma unroll
  for (int k = 0; k < 2; ++k) {
    const int sl = s0 + k;
    const float se = tp[0][sl][d] + tp[1][sl][d];
    const int s = sBase + sl;
    const float dd = de[(size_t)(b * TD_ + s) * D_ + d];
    float* o = out + (size_t)(b * TD_ + s) * (4 * D_);
    o[d] = dd;
    o[D_ + d] = se;
    o[2 * D_ + d] = dd * se;
  }
}

// ---------------------------------------------------------------------------
// K3: max_alphas = softmax_s(maxmu[b,:]); h_hat[b,dchunk] = sum_s de*ma[s];
// then writes out chunk 3 = de * h_hat for all s at its 32 d-columns.
// grid (8 dChunks, 8 b), 256 threads.
// ---------------------------------------------------------------------------
__global__ __launch_bounds__(256) void coatt_k3_hhat(
    const float* __restrict__ de, const float* __restrict__ maxmu,
    float* __restrict__ out) {
  const int b = blockIdx.y;
  const int dBase = blockIdx.x * 32;
  const int tid = threadIdx.x;
  const int w = tid >> 6, lane = tid & 63;
  __shared__ float red[8];
  __shared__ float malpha[256];
  __shared__ float acc_red[256];
  __shared__ float hh_s[32];
  const float vv = maxmu[b * TD_ + tid];
  float m = vv;
#pragma unroll
  for (int off = 32; off > 0; off >>= 1) m = fmaxf(m, __shfl_xor(m, off));
  if (lane == 0) red[w] = m;
  __syncthreads();
  m = fmaxf(fmaxf(red[0], red[1]), fmaxf(red[2], red[3]));
  const float e = fexp2((vv - m) * LOG2E_F);
  float sm = e;
#pragma unroll
  for (int off = 32; off > 0; off >>= 1) sm += __shfl_xor(sm, off);
  if (lane == 0) red[4 + w] = sm;
  __syncthreads();
  sm = (red[4] + red[5]) + (red[6] + red[7]);
  malpha[tid] = e * frcp(sm);
  __syncthreads();
  const int dl = tid & 31, sg = tid >> 5;
  float acc = 0.f;
  for (int s = sg * 32; s < sg * 32 + 32; ++s)
    acc = fmaf(de[(size_t)(b * TD_ + s) * D_ + dBase + dl], malpha[s], acc);
  acc_red[tid] = acc;
  __syncthreads();
  if (tid < 32) {
    float tsum = acc_red[tid];
#pragma unroll
    for (int g = 1; g < 8; ++g) tsum += acc_red[g * 32 + tid];
    hh_s[tid] = tsum;
  }
  __syncthreads();
  const float hh = hh_s[dl];
#pragma unroll 4
  for (int s = sg; s < TD_; s += 8) {
    const float dd = de[(size_t)(b * TD_ + s) * D_ + dBase + dl];
    out[(size_t)(b * TD_ + s) * (4 * D_) + 3 * D_ + dBase + dl] = dd * hh;
  }
}

extern "C" void kernel_launch(void* const* d_in, const int* in_sizes, int n_in,
                              void* d_out, int out_size, void* d_ws, size_t ws_size,
                              hipStream_t stream) {
  (void)in_sizes; (void)n_in; (void)out_size; (void)ws_size;
  const float* en   = (const float*)d_in[0];
  const float* de   = (const float*)d_in[1];
  const float* w_en = (const float*)d_in[2];
  const float* w_de = (const float*)d_in[3];
  const float* nu   = (const float*)d_in[4];
  float* out = (float*)d_out;
  float* ws  = (float*)d_ws;

  coatt_k1_proj<<<dim3(4, 32, 2), 256, 0, stream>>>(
      en, de, w_en, w_de, ws + EET_OFF, ws + ED_OFF);
  coatt_k24<<<dim3(512), 512, 0, stream>>>(
      en, de, nu, ws + EET_OFF, ws + ED_OFF, ws + MAXMU_OFF, out);
  coatt_k3_hhat<<<dim3(8, 8), 256, 0, stream>>>(de, ws + MAXMU_OFF, out);
}

// Round 6
// 113.653 us; speedup vs baseline: 2.8105x; 1.3250x over previous
//
#include <hip/hip_runtime.h>

// Problem constants
#define B_   8
#define TE_  256
#define TD_  256
#define D_   256
#define U_   256

// Workspace layout (float offsets). ~4.2 MB.
// EeT is stored INTERLEAVED: EeT[b][u4][t][j] = exp2(2log2e*ae[b,t,4*u4+j])
// so the K24 u-loop reads one float4 (4 u-values) per lane per iteration.
#define EET_OFF   0        // (B, U/4, TE, 4)
#define ED_OFF    524288   // (B, TD, U)  Ed = exp2(2log2e * de@w_de), row-major
#define MAXMU_OFF 1048576  // (B, TD)     row max of mu'

__device__ __forceinline__ float fexp2(float x) {
#if __has_builtin(__builtin_amdgcn_exp2f)
  return __builtin_amdgcn_exp2f(x);
#else
  return exp2f(x);
#endif
}
__device__ __forceinline__ float frcp(float x) {
#if __has_builtin(__builtin_amdgcn_rcpf)
  return __builtin_amdgcn_rcpf(x);
#else
  return 1.0f / x;
#endif
}

#define LOG2E_F 1.4426950408889634f
#define TWO_LOG2E_F 2.8853900817779268f

// ---------------------------------------------------------------------------
// K1 v4: occupancy-first. Tile 64 rows x 32 U-cols, 512 threads, 2x2
// microtile. grid (8, 32, 2) = 512 blocks -> 2 blocks/CU, 16 waves/CU,
// 4 waves/SIMD (R5 v3 was 1 wave/SIMD, VALUBusy 5% = latency-dead).
//   W-panel (256k x 32c = 32KB) staged to LDS ONCE -> k-loop has ZERO
//   barriers. A: global float4, 16 lanes/address dedup (1 L1 fetch).
//   B: ds_read_b64, bank = 2*tx -> conflict-free.
// LDS reused for the which==0 transpose epilogue (pitch 69).
// ---------------------------------------------------------------------------
__global__ __launch_bounds__(512) void coatt_k1_proj(
    const float* __restrict__ en, const float* __restrict__ de,
    const float* __restrict__ w_en, const float* __restrict__ w_de,
    float* __restrict__ eet, float* __restrict__ edp) {
  const int which = blockIdx.z;  // 0: en->EeT (interleaved), 1: de->Ed (direct)
  const float* __restrict__ A = which ? de : en;     // (2048, 256)
  const float* __restrict__ W = which ? w_de : w_en; // (256, 256)
  const int rowBase = blockIdx.y * 64;   // global row in (B*T)
  const int colBase = blockIdx.x * 32;   // col in U
  __shared__ float Bs[256][32];          // full-K W panel, 32KB
  const int tid = threadIdx.x;           // 0..511
  const int tx = tid & 15, ty = tid >> 4;  // cols tx*2.., rows ty*2.. (ty 0..31)

  // Stage W panel once: thread (r = tid>>1, half = tid&1) loads 16 floats.
  {
    const int r = tid >> 1, h = (tid & 1) * 16;
#pragma unroll
    for (int j = 0; j < 4; ++j)
      *(float4*)&Bs[r][h + j * 4] =
          *(const float4*)&W[(size_t)r * U_ + colBase + h + j * 4];
  }
  __syncthreads();

  float acc[2][2] = {};
#pragma unroll 4
  for (int k4 = 0; k4 < 64; ++k4) {
    float a0[4], a1[4];
    *(float4*)a0 = *(const float4*)&A[(size_t)(rowBase + ty * 2 + 0) * D_ + k4 * 4];
    *(float4*)a1 = *(const float4*)&A[(size_t)(rowBase + ty * 2 + 1) * D_ + k4 * 4];
#pragma unroll
    for (int kk = 0; kk < 4; ++kk) {
      float b[2];
      *(float2*)b = *(const float2*)&Bs[k4 * 4 + kk][tx * 2];
      acc[0][0] = fmaf(a0[kk], b[0], acc[0][0]);
      acc[0][1] = fmaf(a0[kk], b[1], acc[0][1]);
      acc[1][0] = fmaf(a1[kk], b[0], acc[1][0]);
      acc[1][1] = fmaf(a1[kk], b[1], acc[1][1]);
    }
  }

  if (which) {
    // Ed: direct row-major float2 store (128B contiguous per ty-group).
#pragma unroll
    for (int i = 0; i < 2; ++i) {
      float2 o;
      o.x = fexp2(acc[i][0] * TWO_LOG2E_F);
      o.y = fexp2(acc[i][1] * TWO_LOG2E_F);
      *(float2*)&edp[(size_t)(rowBase + ty * 2 + i) * U_ + colBase + tx * 2] = o;
    }
  } else {
    // EeT interleaved: transpose via LDS (reuse Bs; need 32*69=2208 floats).
    __syncthreads();  // all ds_reads of Bs done before overwrite
    float* Cs = &Bs[0][0];
#pragma unroll
    for (int i = 0; i < 2; ++i)
#pragma unroll
      for (int j = 0; j < 2; ++j)
        Cs[(tx * 2 + j) * 69 + ty * 2 + i] = fexp2(acc[i][j] * TWO_LOG2E_F);
    __syncthreads();
    const int b = rowBase >> 8, t0 = rowBase & 255;
    const int u4Base = colBase >> 2;
    const int u4l = tid >> 6, tl = tid & 63;  // 8 u4-groups x 64 t
    float4 v;
    v.x = Cs[(u4l * 4 + 0) * 69 + tl];
    v.y = Cs[(u4l * 4 + 1) * 69 + tl];
    v.z = Cs[(u4l * 4 + 2) * 69 + tl];
    v.w = Cs[(u4l * 4 + 3) * 69 + tl];
    *(float4*)&eet[(size_t)((b * 64 + u4Base + u4l) * 256 + t0 + tl) * 4] = v;
  }
}

// ---------------------------------------------------------------------------
// K24 (fused K2+K4), 512 threads, grid 512. IDENTICAL to R5 (single-variable
// discipline: this round changes only K1).
// ---------------------------------------------------------------------------
__global__ __launch_bounds__(512) void coatt_k24(
    const float* __restrict__ en, const float* __restrict__ de,
    const float* __restrict__ nu, const float* __restrict__ eet,
    const float* __restrict__ edp, float* __restrict__ maxmu,
    float* __restrict__ out) {
  const int id = blockIdx.x;
  const int b = id & 7;             // XCD-aligned under round-robin dispatch
  const int sBase = (id >> 3) * 4;
  const int tid = threadIdx.x;      // 0..511
  const int t = tid & 255;
  const int half = tid >> 8;        // 0/1 -> local s rows {0,1} / {2,3}
  const int w = tid >> 6, lane = tid & 63;

  __shared__ float als[4][256];   // alphas
  __shared__ float tp[2][4][256]; // t-phase partials [half][s][d]
  __shared__ float part[2][8];    // softmax partials [s-local-in-half][wave]

  // Wave-uniform Ed row base -> SGPR (readfirstlane). half is wave-uniform.
  const int edBase =
      __builtin_amdgcn_readfirstlane((b * TD_ + sBase + half * 2) * U_);
  const float* __restrict__ Ed0 = edp + edBase;        // uniform -> s_load
  const float* __restrict__ Ed1 = Ed0 + U_;
  const float* __restrict__ Ee_b = eet + (size_t)b * (U_ * TE_) + t * 4;

  float accA0 = 0.f, accB0 = 0.f, accA1 = 0.f, accB1 = 0.f;  // 2 chains per s
#pragma unroll 4
  for (int u4 = 0; u4 < 64; ++u4) {
    const float4 ee4 = *(const float4*)&Ee_b[u4 * 1024];  // coalesced 16B
    const float4 nv = *(const float4*)&nu[u4 * 4];        // uniform -> SGPR
    const float4 d0 = *(const float4*)&Ed0[u4 * 4];       // uniform -> SGPR
    const float4 d1 = *(const float4*)&Ed1[u4 * 4];       // uniform -> SGPR
    const float* eep = (const float*)&ee4;
    const float* nvp = (const float*)&nv;
    const float* p0 = (const float*)&d0;
    const float* p1 = (const float*)&d1;
#pragma unroll
    for (int j = 0; j < 4; ++j) {
      const float r0 = frcp(fmaf(p0[j], eep[j], 1.0f));
      const float r1 = frcp(fmaf(p1[j], eep[j], 1.0f));
      if (j & 1) {
        accB0 = fmaf(nvp[j], r0, accB0);
        accB1 = fmaf(nvp[j], r1, accB1);
      } else {
        accA0 = fmaf(nvp[j], r0, accA0);
        accA1 = fmaf(nvp[j], r1, accA1);
      }
    }
  }
  float v0 = -2.f * (accA0 + accB0);
  float v1 = -2.f * (accA1 + accB1);

  // Softmax over t for the 2 local s-rows; each covered by the half's 4 waves.
  float m0 = v0, m1 = v1;
#pragma unroll
  for (int off = 32; off > 0; off >>= 1) {
    m0 = fmaxf(m0, __shfl_xor(m0, off));
    m1 = fmaxf(m1, __shfl_xor(m1, off));
  }
  if (lane == 0) { part[0][w] = m0; part[1][w] = m1; }
  __syncthreads();
  const int wb = half * 4;
  m0 = fmaxf(fmaxf(part[0][wb], part[0][wb + 1]),
             fmaxf(part[0][wb + 2], part[0][wb + 3]));
  m1 = fmaxf(fmaxf(part[1][wb], part[1][wb + 1]),
             fmaxf(part[1][wb + 2], part[1][wb + 3]));
  __syncthreads();
  const float e0 = fexp2((v0 - m0) * LOG2E_F);
  const float e1 = fexp2((v1 - m1) * LOG2E_F);
  float sm0 = e0, sm1 = e1;
#pragma unroll
  for (int off = 32; off > 0; off >>= 1) {
    sm0 += __shfl_xor(sm0, off);
    sm1 += __shfl_xor(sm1, off);
  }
  if (lane == 0) { part[0][w] = sm0; part[1][w] = sm1; }
  __syncthreads();
  const float tot0 = (part[0][wb] + part[0][wb + 1]) +
                     (part[0][wb + 2] + part[0][wb + 3]);
  const float tot1 = (part[1][wb] + part[1][wb + 1]) +
                     (part[1][wb + 2] + part[1][wb + 3]);
  const int s0 = half * 2;
  als[s0][t] = e0 * frcp(tot0);
  als[s0 + 1][t] = e1 * frcp(tot1);
  if (t == 0) {
    maxmu[b * TD_ + sBase + s0] = m0;
    maxmu[b * TD_ + sBase + s0 + 1] = m1;
  }
  __syncthreads();

  // Phase t: d = t; halves cover disjoint t-ranges for ALL 4 s-rows.
  const int d = t;
  const int tBeg = half * 128;
  const float* __restrict__ en_b = en + (size_t)b * TE_ * D_ + d;
  float sa0 = 0.f, sa1 = 0.f, sa2 = 0.f, sa3 = 0.f;
#pragma unroll 4
  for (int t4 = 0; t4 < 32; ++t4) {
    const int tt = tBeg + t4 * 4;
    const float4 a0 = *(const float4*)&als[0][tt];  // LDS broadcast
    const float4 a1 = *(const float4*)&als[1][tt];
    const float4 a2 = *(const float4*)&als[2][tt];
    const float4 a3 = *(const float4*)&als[3][tt];
    float env[4];
#pragma unroll
    for (int j = 0; j < 4; ++j) env[j] = en_b[(size_t)(tt + j) * D_];  // coalesced
    const float* q0 = (const float*)&a0;
    const float* q1 = (const float*)&a1;
    const float* q2 = (const float*)&a2;
    const float* q3 = (const float*)&a3;
#pragma unroll
    for (int j = 0; j < 4; ++j) {
      sa0 = fmaf(q0[j], env[j], sa0);
      sa1 = fmaf(q1[j], env[j], sa1);
      sa2 = fmaf(q2[j], env[j], sa2);
      sa3 = fmaf(q3[j], env[j], sa3);
    }
  }
  tp[half][0][d] = sa0;
  tp[half][1][d] = sa1;
  tp[half][2][d] = sa2;
  tp[half][3][d] = sa3;
  __syncthreads();
#pragma unroll
  for (int k = 0; k < 2; ++k) {
    const int sl = s0 + k;
    const float se = tp[0][sl][d] + tp[1][sl][d];
    const int s = sBase + sl;
    const float dd = de[(size_t)(b * TD_ + s) * D_ + d];
    float* o = out + (size_t)(b * TD_ + s) * (4 * D_);
    o[d] = dd;
    o[D_ + d] = se;
    o[2 * D_ + d] = dd * se;
  }
}

// ---------------------------------------------------------------------------
// K3: max_alphas = softmax_s(maxmu[b,:]); h_hat[b,dchunk] = sum_s de*ma[s];
// then writes out chunk 3 = de * h_hat. grid (8, 8), 256 threads.
// IDENTICAL to R5.
// ---------------------------------------------------------------------------
__global__ __launch_bounds__(256) void coatt_k3_hhat(
    const float* __restrict__ de, const float* __restrict__ maxmu,
    float* __restrict__ out) {
  const int b = blockIdx.y;
  const int dBase = blockIdx.x * 32;
  const int tid = threadIdx.x;
  const int w = tid >> 6, lane = tid & 63;
  __shared__ float red[8];
  __shared__ float malpha[256];
  __shared__ float acc_red[256];
  __shared__ float hh_s[32];
  const float vv = maxmu[b * TD_ + tid];
  float m = vv;
#pragma unroll
  for (int off = 32; off > 0; off >>= 1) m = fmaxf(m, __shfl_xor(m, off));
  if (lane == 0) red[w] = m;
  __syncthreads();
  m = fmaxf(fmaxf(red[0], red[1]), fmaxf(red[2], red[3]));
  const float e = fexp2((vv - m) * LOG2E_F);
  float sm = e;
#pragma unroll
  for (int off = 32; off > 0; off >>= 1) sm += __shfl_xor(sm, off);
  if (lane == 0) red[4 + w] = sm;
  __syncthreads();
  sm = (red[4] + red[5]) + (red[6] + red[7]);
  malpha[tid] = e * frcp(sm);
  __syncthreads();
  const int dl = tid & 31, sg = tid >> 5;
  float acc = 0.f;
  for (int s = sg * 32; s < sg * 32 + 32; ++s)
    acc = fmaf(de[(size_t)(b * TD_ + s) * D_ + dBase + dl], malpha[s], acc);
  acc_red[tid] = acc;
  __syncthreads();
  if (tid < 32) {
    float tsum = acc_red[tid];
#pragma unroll
    for (int g = 1; g < 8; ++g) tsum += acc_red[g * 32 + tid];
    hh_s[tid] = tsum;
  }
  __syncthreads();
  const float hh = hh_s[dl];
#pragma unroll 4
  for (int s = sg; s < TD_; s += 8) {
    const float dd = de[(size_t)(b * TD_ + s) * D_ + dBase + dl];
    out[(size_t)(b * TD_ + s) * (4 * D_) + 3 * D_ + dBase + dl] = dd * hh;
  }
}

extern "C" void kernel_launch(void* const* d_in, const int* in_sizes, int n_in,
                              void* d_out, int out_size, void* d_ws, size_t ws_size,
                              hipStream_t stream) {
  (void)in_sizes; (void)n_in; (void)out_size; (void)ws_size;
  const float* en   = (const float*)d_in[0];
  const float* de   = (const float*)d_in[1];
  const float* w_en = (const float*)d_in[2];
  const float* w_de = (const float*)d_in[3];
  const float* nu   = (const float*)d_in[4];
  float* out = (float*)d_out;
  float* ws  = (float*)d_ws;

  coatt_k1_proj<<<dim3(8, 32, 2), 512, 0, stream>>>(
      en, de, w_en, w_de, ws + EET_OFF, ws + ED_OFF);
  coatt_k24<<<dim3(512), 512, 0, stream>>>(
      en, de, nu, ws + EET_OFF, ws + ED_OFF, ws + MAXMU_OFF, out);
  coatt_k3_hhat<<<dim3(8, 8), 256, 0, stream>>>(de, ws + MAXMU_OFF, out);
}